// Round 7
// baseline (1076.667 us; speedup 1.0000x reference)
//
#include <hip/hip_runtime.h>
#include <hip/hip_fp16.h>

#define B_   32
#define T_   256
#define D_   1024
#define H_   8
#define HID_ 256

typedef unsigned short u16;
typedef __attribute__((ext_vector_type(8))) short  s16x8;
typedef __attribute__((ext_vector_type(8))) __bf16 bf16x8;
typedef __attribute__((ext_vector_type(4))) float  f32x4;
typedef __attribute__((ext_vector_type(2))) float  f32x2;
typedef __attribute__((ext_vector_type(2))) _Float16 h2v;
typedef __attribute__((ext_vector_type(8))) _Float16 h8;

__device__ __forceinline__ u16 f2bf(float f){
  union { float f; unsigned u; } v; v.f = f;
  unsigned r = v.u + 0x7FFFu + ((v.u >> 16) & 1u);   // RNE
  return (u16)(r >> 16);
}
__device__ __forceinline__ float bf2f(u16 u){
  union { unsigned u; float f; } v; v.u = ((unsigned)u) << 16; return v.f;
}

__device__ __forceinline__ f32x4 mfma_bf16(s16x8 a, s16x8 b, f32x4 c){
  bf16x8 av, bv;
  __builtin_memcpy(&av, &a, 16);
  __builtin_memcpy(&bv, &b, 16);
  return __builtin_amdgcn_mfma_f32_16x16x32_bf16(av, bv, c, 0, 0, 0);
}

__device__ __forceinline__ void gld16(const void* g, void* l){
  __builtin_amdgcn_global_load_lds((const __attribute__((address_space(1))) void*)g,
                                   (__attribute__((address_space(3))) void*)l, 16, 0, 0);
}

#if defined(__has_builtin)
#if __has_builtin(__builtin_amdgcn_fdot2)
#define HAVE_FDOT2 1
#endif
#endif

__device__ __forceinline__ float fdot2f(h2v a, h2v b, float c){
#ifdef HAVE_FDOT2
  return __builtin_amdgcn_fdot2(a, b, c, false);
#else
  return c + (float)a[0]*(float)b[0] + (float)a[1]*(float)b[1];
#endif
}

// fp8 (e4m3-class, HW-consistent encode/decode) pair -> 2 x f16 (bitcast returns)
__device__ __forceinline__ h2v dec2(short s){
  h2v r;
#if defined(__has_builtin) && __has_builtin(__builtin_amdgcn_cvt_pk_f16_fp8)
  auto p = __builtin_amdgcn_cvt_pk_f16_fp8(s);
  __builtin_memcpy(&r, &p, 4);
#else
  f32x2 f = __builtin_amdgcn_cvt_pk_f32_fp8((int)(unsigned short)s, false);
  auto p = __builtin_amdgcn_cvt_pkrtz(f[0], f[1]);   // exact: fp8 subset of f16
  __builtin_memcpy(&r, &p, 4);
#endif
  return r;
}

// ---------- x -> h (bf16 first 1024 cols) + xfb (bf16 last 1536 cols) ----------
__global__ void k_conv_x(const float* __restrict__ x, u16* __restrict__ h,
                         u16* __restrict__ xfb){
  int m = blockIdx.x;
  int i = threadIdx.x * 8;                 // 320 threads * 8 = 2560
  const float4* p = (const float4*)(x + (size_t)m*2560 + i);
  float4 a = p[0], b = p[1];
  union { u16 u[8]; uint4 v; } o;
  o.u[0]=f2bf(a.x); o.u[1]=f2bf(a.y); o.u[2]=f2bf(a.z); o.u[3]=f2bf(a.w);
  o.u[4]=f2bf(b.x); o.u[5]=f2bf(b.y); o.u[6]=f2bf(b.z); o.u[7]=f2bf(b.w);
  u16* dst = (i < 1024) ? (h + (size_t)m*1024 + i) : (xfb + (size_t)m*1536 + (i-1024));
  *(uint4*)dst = o.v;
}

// ---------- merged weight-prep switchboard (256 thr/block) ----------
__device__ void transpose_tile(const float* __restrict__ in, u16* __restrict__ out,
                               int K, int N, int kb, int nb, int tid,
                               u16 (*tile)[65]){
  {
    int k  = tid >> 2;
    int n0 = (tid & 3) * 16;
    const float* ip = in + (size_t)(kb + k) * N + nb + n0;
    #pragma unroll
    for (int i = 0; i < 4; ++i){
      float4 v = *(const float4*)(ip + i*4);
      tile[k][n0 + i*4 + 0] = f2bf(v.x);
      tile[k][n0 + i*4 + 1] = f2bf(v.y);
      tile[k][n0 + i*4 + 2] = f2bf(v.z);
      tile[k][n0 + i*4 + 3] = f2bf(v.w);
    }
  }
  __syncthreads();
  {
    int n  = tid >> 2;
    int k0 = (tid & 3) * 16;
    union { u16 u[16]; uint4 v[2]; } p;
    #pragma unroll
    for (int i = 0; i < 16; ++i) p.u[i] = tile[k0 + i][n];
    uint4* op = (uint4*)(out + (size_t)(nb + n) * K + kb + k0);
    op[0] = p.v[0]; op[1] = p.v[1];
  }
}

__global__ void k_prep(const float* __restrict__ Wq, const float* __restrict__ Wk,
                       const float* __restrict__ Wv, const float* __restrict__ Wo,
                       const float* __restrict__ Wtran,
                       const float* __restrict__ Wihf, const float* __restrict__ Wihb,
                       const float* __restrict__ Whhf, const float* __restrict__ Whhb,
                       const float* __restrict__ bq, const float* __restrict__ bk,
                       const float* __restrict__ bv,
                       const float* __restrict__ bihf, const float* __restrict__ bihb,
                       const int* __restrict__ mask,
                       u16* __restrict__ WqkvT, u16* __restrict__ WoT,
                       u16* __restrict__ WtranT, u16* __restrict__ WihCat,
                       int* __restrict__ Wp, float* __restrict__ qkvB,
                       float* __restrict__ bihCat, int* __restrict__ lens)
{
  __shared__ u16 tile[64][65];
  int bid = blockIdx.x, tid = threadIdx.x;
  const size_t M1 = (size_t)D_ * D_;                     // 1048576

  if (bid < 2048){                                        // 8 DxD transposes
    int m = bid >> 8, t = bid & 255;
    int l = m >> 2, which = m & 3;
    const float* src; u16* dst;
    if (which == 0){ src = Wq + l*M1; dst = WqkvT + l*3*M1; }
    else if (which == 1){ src = Wk + l*M1; dst = WqkvT + l*3*M1 + M1; }
    else if (which == 2){ src = Wv + l*M1; dst = WqkvT + l*3*M1 + 2*M1; }
    else { src = Wo + l*M1; dst = WoT + l*M1; }
    transpose_tile(src, dst, D_, D_, (t >> 4)*64, (t & 15)*64, tid, tile);
  } else if (bid < 2240){                                 // Wtran [1536x512] -> NK
    int t = bid - 2048;
    transpose_tile(Wtran, WtranT, 1536, 512, (t >> 3)*64, (t & 7)*64, tid, tile);
  } else if (bid < 3008){                                 // Wih f+b -> bf16 cat
    int i0 = (bid - 2240)*2048 + tid*8;
    const float* src = (i0 < 786432) ? (Wihf + i0) : (Wihb + (i0 - 786432));
    float4 a = *(const float4*)src, b = *(const float4*)(src + 4);
    union { u16 u[8]; uint4 v; } o;
    o.u[0]=f2bf(a.x); o.u[1]=f2bf(a.y); o.u[2]=f2bf(a.z); o.u[3]=f2bf(a.w);
    o.u[4]=f2bf(b.x); o.u[5]=f2bf(b.y); o.u[6]=f2bf(b.z); o.u[7]=f2bf(b.w);
    *(uint4*)(WihCat + i0) = o.v;
  } else if (bid < 3392){                                 // Whh -> fp8 x64, GRU layout
    int o = (bid - 3008)*256 + tid;                       // 98304 dwords total
    int dir = o / 49152, r = o - dir*49152;
    int tid2 = r / 48, q = r - tid2*48;
    int g = q >> 4, c = (q & 15) >> 1, di = q & 1;
    int j = tid2 >> 2, kc = tid2 & 3;
    int row = g*256 + j;
    int k0 = (c*4 + kc)*8 + di*4;
    const float* W = dir ? Whhb : Whhf;
    const float* wsrc = W + (size_t)row*256 + k0;
    int d = __builtin_amdgcn_cvt_pk_fp8_f32(wsrc[0]*64.f, wsrc[1]*64.f, 0, false);
    d     = __builtin_amdgcn_cvt_pk_fp8_f32(wsrc[2]*64.f, wsrc[3]*64.f, d, true);
    Wp[o] = d;
  } else if (bid < 3400){                                 // biases
    int base = (bid - 3392)*1024 + tid*4;
    #pragma unroll
    for (int e = 0; e < 4; ++e){
      int i = base + e;
      if (i >= 7680) break;
      if (i < 6144){
        int l = i / 3072, r = i - l*3072;
        float v = (r < 1024) ? bq[l*1024 + r]
                : (r < 2048) ? bk[l*1024 + r - 1024]
                             : bv[l*1024 + r - 2048];
        qkvB[i] = v;
      } else {
        int r = i - 6144;
        bihCat[r] = (r < 768) ? bihf[r] : bihb[r - 768];
      }
    }
  } else {                                                // lengths (32 blocks)
    int b = bid - 3400;
    int v = mask[b * T_ + tid];
    #pragma unroll
    for (int off = 1; off < 64; off <<= 1) v += __shfl_xor(v, off);
    __shared__ int s[4];
    if ((tid & 63) == 0) s[tid >> 6] = v;
    __syncthreads();
    if (tid == 0) lens[b] = s[0] + s[1] + s[2] + s[3];
  }
}

// ---------- GEMM: out[M,N] = A[M,K](bf16,lda) @ Wb[N,K](bf16)^T + bias (+res) ----
// 128x128 tile, BK=32, 256 threads (4 waves 2x2, each 64x64), global_load_lds x16.
// MODE: 0 f32 out; 1 bf16 out; 2 bf16 out + bf16 res; 3 f32 out + f32 res.
template<int MODE>
__global__ __launch_bounds__(256, 2)
void k_gemm(const u16* __restrict__ A, int lda,
            const u16* __restrict__ Wb,
            const float* __restrict__ bias,
            const void* __restrict__ resv,
            void* __restrict__ outv,
            int K, int N)
{
  __shared__ __align__(16) u16 As[4*128*8];  // [kh][row][8]
  __shared__ __align__(16) u16 Bs[4*128*8];  // [kh][n][8]
  int tid = threadIdx.x;
  int n0 = blockIdx.x * 128, m0 = blockIdx.y * 128;
  int lane = tid & 63, w = tid >> 6;
  int wm = w >> 1, wn = w & 1;
  int lrow = lane & 15, lq = lane >> 4;
  f32x4 acc[4][4] = {};

  int row = tid & 127;
  int kh0 = tid >> 7;                               // 0..1 (second chunk is +2)
  const u16* aG0 = A  + (size_t)(m0 + row) * lda + kh0 * 8;
  const u16* bG0 = Wb + (size_t)(n0 + row) * K   + kh0 * 8;
  u16* aL0 = &As[((kh0    )*128 + row) * 8];
  u16* aL1 = &As[((kh0 + 2)*128 + row) * 8];
  u16* bL0 = &Bs[((kh0    )*128 + row) * 8];
  u16* bL1 = &Bs[((kh0 + 2)*128 + row) * 8];

  for (int k0 = 0; k0 < K; k0 += 32){
    gld16(aG0 + k0,      aL0);
    gld16(aG0 + k0 + 16, aL1);
    gld16(bG0 + k0,      bL0);
    gld16(bG0 + k0 + 16, bL1);
    __syncthreads();

    s16x8 af[4], bfr[4];
    #pragma unroll
    for (int mt = 0; mt < 4; ++mt)
      af[mt] = *(const s16x8*)&As[(lq*128 + wm*64 + mt*16 + lrow) * 8];
    #pragma unroll
    for (int nt = 0; nt < 4; ++nt)
      bfr[nt] = *(const s16x8*)&Bs[(lq*128 + wn*64 + nt*16 + lrow) * 8];
    #pragma unroll
    for (int mt = 0; mt < 4; ++mt)
      #pragma unroll
      for (int nt = 0; nt < 4; ++nt)
        acc[mt][nt] = mfma_bf16(af[mt], bfr[nt], acc[mt][nt]);
    __syncthreads();
  }

  #pragma unroll
  for (int mt = 0; mt < 4; ++mt){
    int rowb = m0 + wm*64 + mt*16 + lq*4;
    #pragma unroll
    for (int nt = 0; nt < 4; ++nt){
      int col = n0 + wn*64 + nt*16 + lrow;
      float bcol = bias[col];
      f32x4 a = acc[mt][nt];
      #pragma unroll
      for (int r = 0; r < 4; ++r){
        size_t idx = (size_t)(rowb + r) * N + col;
        float v = a[r] + bcol;
        if (MODE == 2) v += bf2f(((const u16*)resv)[idx]);
        if (MODE == 3) v += ((const float*)resv)[idx];
        if (MODE == 0 || MODE == 3) ((float*)outv)[idx] = v;
        else                        ((u16*)outv)[idx]   = f2bf(v);
      }
    }
  }
}

// ---------- banded attention (window +-3), 4 waves/block, one wave per (b,h,t) ----
__global__ void k_attn(const u16* __restrict__ qkv, u16* __restrict__ ao){
  int lane = threadIdx.x & 63, wv = threadIdx.x >> 6;
  int bid = blockIdx.x;
  int t  = (bid & 63) * 4 + wv;
  int hh = (bid >> 6) & 7;
  int b  = bid >> 9;
  size_t qb = ((size_t)b*T_ + t)*3072 + hh*128 + lane*2;
  float2 q2;
  { ushort2 u = *(const ushort2*)(qkv + qb); q2.x = bf2f(u.x); q2.y = bf2f(u.y); }
  int jlo = t - 3; if (jlo < 0) jlo = 0;
  int jhi = t + 3; if (jhi > T_ - 1) jhi = T_ - 1;
  const float scale = 0.08838834764831845f;   // 1/sqrt(128)
  float m = -1e30f, sum = 0.f;
  float ox = 0.f, oy = 0.f;
  for (int j = jlo; j <= jhi; ++j){
    size_t kb = ((size_t)b*T_ + j)*3072 + 1024 + hh*128 + lane*2;
    float2 k2, v2;
    { ushort2 u = *(const ushort2*)(qkv + kb);        k2.x = bf2f(u.x); k2.y = bf2f(u.y); }
    { ushort2 u = *(const ushort2*)(qkv + kb + 1024); v2.x = bf2f(u.x); v2.y = bf2f(u.y); }
    float s = q2.x*k2.x + q2.y*k2.y;
    s += __shfl_xor(s, 1);  s += __shfl_xor(s, 2);  s += __shfl_xor(s, 4);
    s += __shfl_xor(s, 8);  s += __shfl_xor(s, 16); s += __shfl_xor(s, 32);
    float f  = s * scale;
    float nm = fmaxf(m, f);
    float c  = __expf(m - nm);
    float p  = __expf(f - nm);
    sum = sum*c + p;
    ox = ox*c + p*v2.x;
    oy = oy*c + p*v2.y;
    m = nm;
  }
  float inv = 1.f / sum;
  size_t ob = ((size_t)b*T_ + t)*1024 + hh*128 + lane*2;
  ushort2 r; r.x = f2bf(ox*inv); r.y = f2bf(oy*inv);
  *(ushort2*)(ao + ob) = r;
}

// ---------- GRU scan: 1024 thr/block, one block per (dir,b), fp8 W_hh in VGPRs ----
// thread = (j, kc): j = tid>>2 row, kc = tid&3 k-quarter (interleaved 16B f16 chunks).
// fp8 weights = 48 VGPRs/thread (vs 192 f16) -> register-resident fits the RA's budget.
__global__ __attribute__((amdgpu_flat_work_group_size(1024,1024), amdgpu_waves_per_eu(4,4)))
void k_gru(const int* __restrict__ Wp,
           const float* __restrict__ bhhF, const float* __restrict__ bhhB,
           const float* __restrict__ gx,   // [B*T][1536]: dir*768 + {r,z,n}*256
           const int* __restrict__ lengths, float* __restrict__ out)
{
  int dir = blockIdx.x >> 5, b = blockIdx.x & 31;
  const float* bhh = dir ? bhhB : bhhF;
  int tid = threadIdx.x;
  int j = tid >> 2, kc = tid & 3;

  int wv[48];                                         // [g][c][di]: g*16 + c*2 + di
  {
    const uint4* wp4 = (const uint4*)(Wp + (size_t)dir*49152 + (size_t)tid*48);
    #pragma unroll
    for (int c = 0; c < 12; ++c){
      uint4 t4 = wp4[c];
      wv[c*4+0]=(int)t4.x; wv[c*4+1]=(int)t4.y; wv[c*4+2]=(int)t4.z; wv[c*4+3]=(int)t4.w;
    }
  }
  #pragma unroll
  for (int i = 0; i < 48; ++i) asm volatile("" : "+v"(wv[i]));

  float bb0 = bhh[j], bb1 = bhh[256 + j], bb2 = bhh[512 + j];

  __shared__ __align__(16) _Float16 hc[2][256];
  if (tid < 256) hc[0][tid] = (_Float16)0.f;
  int len = lengths[b];
  if (tid < 256){
    for (int t = len; t < T_; ++t)
      out[((size_t)b*T_ + t)*512 + dir*256 + tid] = 0.f;
  }
  float hprev = 0.f;
  float gR = 0.f, gZ = 0.f, gN = 0.f;
  if (kc == 0 && len > 0){
    int tt0 = dir ? (len - 1) : 0;
    size_t gb = ((size_t)b*T_ + tt0)*1536 + dir*768 + j;
    gR = gx[gb]; gZ = gx[gb + 256]; gN = gx[gb + 512];
  }
  __syncthreads();

  for (int s = 0; s < len; ++s){
    float nR = 0.f, nZ = 0.f, nN = 0.f;
    if (kc == 0 && s + 1 < len){
      int tn = dir ? (len - 2 - s) : (s + 1);
      size_t gb = ((size_t)b*T_ + tn)*1536 + dir*768 + j;
      nR = gx[gb]; nZ = gx[gb + 256]; nN = gx[gb + 512];
    }
    const _Float16* hbuf = hc[s & 1];
    float aR = 0.f, aZ = 0.f, aN = 0.f;
    #pragma unroll
    for (int c = 0; c < 8; ++c){
      h8 hv = *(const h8*)(hbuf + (c*4 + kc)*8);
      h2v hp0 = (h2v){hv[0], hv[1]}, hp1 = (h2v){hv[2], hv[3]},
          hp2 = (h2v){hv[4], hv[5]}, hp3 = (h2v){hv[6], hv[7]};
#define GATE(g, AC) { int lo = wv[(g)*16 + c*2], hi = wv[(g)*16 + c*2 + 1];   \
      AC = fdot2f(dec2((short)(lo & 0xffff)), hp0, AC);                        \
      AC = fdot2f(dec2((short)(((unsigned)lo) >> 16)), hp1, AC);               \
      AC = fdot2f(dec2((short)(hi & 0xffff)), hp2, AC);                        \
      AC = fdot2f(dec2((short)(((unsigned)hi) >> 16)), hp3, AC); }
      GATE(0, aR) GATE(1, aZ) GATE(2, aN)
#undef GATE
    }
    aR += __shfl_xor(aR, 1); aR += __shfl_xor(aR, 2);
    aZ += __shfl_xor(aZ, 1); aZ += __shfl_xor(aZ, 2);
    aN += __shfl_xor(aN, 1); aN += __shfl_xor(aN, 2);
    if (kc == 0){
      int tt = dir ? (len - 1 - s) : s;
      float r = 1.f / (1.f + __expf(-(gR + aR*0.015625f + bb0)));
      float z = 1.f / (1.f + __expf(-(gZ + aZ*0.015625f + bb1)));
      float e = __expf(2.f*(gN + r*(aN*0.015625f + bb2)));
      float n = 1.f - 2.f/(e + 1.f);                 // tanh
      float hnew = (1.f - z)*n + z*hprev;
      hprev = hnew;
      out[((size_t)b*T_ + tt)*512 + dir*256 + j] = hnew;
      hc[(s + 1) & 1][j] = (_Float16)hnew;
    }
    gR = nR; gZ = nZ; gN = nN;
    __syncthreads();
  }
}

extern "C" void kernel_launch(void* const* d_in, const int* in_sizes, int n_in,
                              void* d_out, int out_size, void* d_ws, size_t ws_size,
                              hipStream_t stream)
{
  const float* x     = (const float*)d_in[0];
  const int*   mask  = (const int*)  d_in[1];
  const float* Wtran = (const float*)d_in[2];
  const float* btran = (const float*)d_in[3];
  const float* Wq    = (const float*)d_in[4];
  const float* bq    = (const float*)d_in[5];
  const float* Wk    = (const float*)d_in[6];
  const float* bk    = (const float*)d_in[7];
  const float* Wv    = (const float*)d_in[8];
  const float* bv    = (const float*)d_in[9];
  const float* Wo    = (const float*)d_in[10];
  const float* bo    = (const float*)d_in[11];
  const float* Wihf  = (const float*)d_in[12];
  const float* Whhf  = (const float*)d_in[13];
  const float* bihf  = (const float*)d_in[14];
  const float* bhhf  = (const float*)d_in[15];
  const float* Wihb  = (const float*)d_in[16];
  const float* Whhb  = (const float*)d_in[17];
  const float* bihb  = (const float*)d_in[18];
  const float* bhhb  = (const float*)d_in[19];
  float* out = (float*)d_out;

  char* ws = (char*)d_ws;
  u16* h      = (u16*)(ws);                                // 16.8 MB
  u16* xfb    = (u16*)(ws + 16777216);                     // 25.2 MB
  u16* ao     = (u16*)(ws + 41943040);                     // 16.8 MB
  u16* qkv    = (u16*)(ws + 58720256);                     // 50.3 MB (gx overlays)
  float* gx   = (float*)qkv;                               // fp32 [MT][1536], same size
  u16* WtranT = (u16*)(ws + 109051904);                    // 1.6 MB
  u16* WqkvT  = (u16*)(ws + 110624768);                    // 12.6 MB
  u16* WoT    = (u16*)(ws + 123207680);                    // 4.2 MB
  u16* WihCat = (u16*)(ws + 127401984);                    // 3.1 MB  [1536][1024]
  int* Wp     = (int*)(ws + 130547712);                    // 384 KB fp8 GRU weights
  float* qkvB  = (float*)(ws + 131334144);                 // 2 x 3072
  float* bihCat= (float*)(ws + 131358720);                 // 1536
  int* lens    = (int*)(ws + 131364864);

  // --- prep: one switchboard kernel + x conversion ---
  k_prep<<<3432, 256, 0, stream>>>(Wq, Wk, Wv, Wo, Wtran, Wihf, Wihb, Whhf, Whhb,
                                   bq, bk, bv, bihf, bihb, mask,
                                   WqkvT, WoT, WtranT, WihCat, Wp, qkvB, bihCat, lens);
  k_conv_x<<<8192, 320, 0, stream>>>(x, h, xfb);

  // --- 2 transformer layers ---
  for (int l = 0; l < 2; ++l){
    size_t qo = (size_t)l * 3 * D_ * D_;
    size_t wo = (size_t)l * D_ * D_;
    k_gemm<1><<<dim3(24,64), 256, 0, stream>>>(h, D_, WqkvT + qo, qkvB + l*3072,
                                               nullptr, qkv, D_, 3072);
    k_attn<<<16384, 256, 0, stream>>>(qkv, ao);
    k_gemm<2><<<dim3(8,64), 256, 0, stream>>>(ao, D_, WoT + wo, bo + l*D_,
                                              h, h, D_, D_);
  }

  // --- GRU input GEMM (both dirs fused) + fused bidirectional scan ---
  k_gemm<0><<<dim3(12,64), 256, 0, stream>>>(h, D_, WihCat, bihCat,
                                             nullptr, gx, D_, 1536);
  k_gru<<<64, 1024, 0, stream>>>(Wp, bhhf, bhhb, gx, lens, out);

  // --- final: d_out += x[:, :, 1024:] @ W_tran + b_tran ---
  k_gemm<3><<<dim3(4,64), 256, 0, stream>>>(xfb, 1536, WtranT, btran,
                                            out, out, 1536, 512);
}